// Round 1
// baseline (224.712 us; speedup 1.0000x reference)
//
#include <hip/hip_runtime.h>
#include <hip/hip_bf16.h>

#define BDIM   256
#define BATCH  32
#define CH     128
#define NLEN   65536
#define NV4    (NLEN / 4)      // 16384 float4 per row
#define KSEL   6553            // int(65536 * 0.1)

// ---------------------------------------------------------------------------
// Kernel 1: scores[b,n] = |sum_c x[b,c,n]*W[c] + bias|   (memory-bound, 1 GiB)
// ---------------------------------------------------------------------------
__global__ __launch_bounds__(BDIM) void conv_score_kernel(
    const float* __restrict__ x, const float* __restrict__ W,
    const float* __restrict__ bias, float* __restrict__ scores) {
  __shared__ float sW[CH];
  if (threadIdx.x < CH) sW[threadIdx.x] = W[threadIdx.x];
  __syncthreads();

  int g   = blockIdx.x * BDIM + threadIdx.x;   // 0 .. B*N/4 - 1
  int row = g >> 14;                           // g / NV4
  int n4  = g & (NV4 - 1);

  const float4* xp = (const float4*)x + (size_t)row * CH * NV4 + n4;
  float4 acc = make_float4(0.f, 0.f, 0.f, 0.f);
#pragma unroll 8
  for (int c = 0; c < CH; ++c) {
    float4 v = xp[(size_t)c * NV4];
    float  w = sW[c];
    acc.x = fmaf(v.x, w, acc.x);
    acc.y = fmaf(v.y, w, acc.y);
    acc.z = fmaf(v.z, w, acc.z);
    acc.w = fmaf(v.w, w, acc.w);
  }
  float bb = bias[0];
  float4 r;
  r.x = fabsf(acc.x + bb);
  r.y = fabsf(acc.y + bb);
  r.z = fabsf(acc.z + bb);
  r.w = fabsf(acc.w + bb);
  ((float4*)scores)[(size_t)row * NV4 + n4] = r;
}

// ---------------------------------------------------------------------------
// Kernel 2: exact top-k mean per row via 3-level radix select on float bits.
// Nonnegative floats compare identically as uint32, so radix-select on the
// bit pattern is exact (including ties: all equal bits == equal values).
// ---------------------------------------------------------------------------
__device__ __forceinline__ int waveReduceI(int v) {
#pragma unroll
  for (int o = 32; o > 0; o >>= 1) v += __shfl_down(v, o);
  return v;
}
__device__ __forceinline__ float waveReduceF(float v) {
#pragma unroll
  for (int o = 32; o > 0; o >>= 1) v += __shfl_down(v, o);
  return v;
}

// Descending-suffix search over hist[4096] for the bucket where the running
// (from the top) count crosses `need`. Hierarchical: thread partials (4
// buckets each) -> wave sums -> serial walk of <=16+64+4 steps by thread 0.
// Result: ctrl[0] = bucket T, ctrl[1] = remaining need inside bucket T.
__device__ void findBucket(int* hist, int* part, int* waveSum, int* ctrl,
                           int need_in, int tid, int lane, int w) {
  int base = tid * 4;
  int s = 0;
#pragma unroll
  for (int j = 0; j < 4; ++j) s += hist[4095 - (base + j)];
  part[tid] = s;
  int wsum = waveReduceI(s);
  if (lane == 0) waveSum[w] = wsum;
  __syncthreads();
  if (tid == 0) {
    int cum = 0, need = need_in;
    int cw = 0;
    for (; cw < 15; ++cw) {
      if (cum + waveSum[cw] >= need) break;
      cum += waveSum[cw];
    }
    int ct = cw * 64;
    for (; ct < cw * 64 + 63; ++ct) {
      if (cum + part[ct] >= need) break;
      cum += part[ct];
    }
    int T = 0;
    int p = ct * 4;
#pragma unroll
    for (int j = 0; j < 4; ++j) {
      int b = 4095 - (p + j);
      int c = hist[b];
      if (cum + c >= need) { T = b; break; }
      cum += c;
    }
    ctrl[0] = T;
    ctrl[1] = need - cum;
  }
  __syncthreads();
}

__global__ __launch_bounds__(1024) void topk_mean_kernel(
    const float* __restrict__ scores, float* __restrict__ out) {
  __shared__ int   hist[4096];
  __shared__ int   part[1024];
  __shared__ int   waveSum[16];
  __shared__ float fws[16];
  __shared__ int   ctrl[2];

  const int tid  = threadIdx.x;
  const int lane = tid & 63;
  const int w    = tid >> 6;
  const int row  = blockIdx.x;
  const float4* sp = (const float4*)(scores + (size_t)row * NLEN);

  // Cache the whole row in registers: 16 x uint4 = 64 VGPRs.
  uint4 uv[16];
#pragma unroll
  for (int i = 0; i < 16; ++i) {
    float4 v = sp[i * 1024 + tid];
    uv[i].x = __float_as_uint(v.x);
    uv[i].y = __float_as_uint(v.y);
    uv[i].z = __float_as_uint(v.z);
    uv[i].w = __float_as_uint(v.w);
  }

  // ---- level 1: bits 30..19 (u >> 19 < 4096 since sign bit is 0)
  for (int i = tid; i < 4096; i += 1024) hist[i] = 0;
  __syncthreads();
#pragma unroll
  for (int i = 0; i < 16; ++i) {
    atomicAdd(&hist[uv[i].x >> 19], 1);
    atomicAdd(&hist[uv[i].y >> 19], 1);
    atomicAdd(&hist[uv[i].z >> 19], 1);
    atomicAdd(&hist[uv[i].w >> 19], 1);
  }
  __syncthreads();
  findBucket(hist, part, waveSum, ctrl, KSEL, tid, lane, w);
  const unsigned T1    = (unsigned)ctrl[0];
  const int      need1 = ctrl[1];

  // ---- level 2: bits 18..7 among elements whose top bits == T1
  for (int i = tid; i < 4096; i += 1024) hist[i] = 0;
  __syncthreads();
#pragma unroll
  for (int i = 0; i < 16; ++i) {
    unsigned a;
    a = uv[i].x; if ((a >> 19) == T1) atomicAdd(&hist[(a >> 7) & 4095], 1);
    a = uv[i].y; if ((a >> 19) == T1) atomicAdd(&hist[(a >> 7) & 4095], 1);
    a = uv[i].z; if ((a >> 19) == T1) atomicAdd(&hist[(a >> 7) & 4095], 1);
    a = uv[i].w; if ((a >> 19) == T1) atomicAdd(&hist[(a >> 7) & 4095], 1);
  }
  __syncthreads();
  findBucket(hist, part, waveSum, ctrl, need1, tid, lane, w);
  const unsigned prefix23 = (T1 << 12) | (unsigned)ctrl[0];  // == u >> 7
  const int      need2    = ctrl[1];

  // ---- level 3: bits 6..0 among elements whose (u >> 7) == prefix23
  for (int i = tid; i < 4096; i += 1024) hist[i] = 0;
  __syncthreads();
#pragma unroll
  for (int i = 0; i < 16; ++i) {
    unsigned a;
    a = uv[i].x; if ((a >> 7) == prefix23) atomicAdd(&hist[a & 127], 1);
    a = uv[i].y; if ((a >> 7) == prefix23) atomicAdd(&hist[a & 127], 1);
    a = uv[i].z; if ((a >> 7) == prefix23) atomicAdd(&hist[a & 127], 1);
    a = uv[i].w; if ((a >> 7) == prefix23) atomicAdd(&hist[a & 127], 1);
  }
  __syncthreads();
  findBucket(hist, part, waveSum, ctrl, need2, tid, lane, w);
  const unsigned vstar = (prefix23 << 7) | (unsigned)ctrl[0];  // k-th largest

  // ---- final: sum of strictly-greater + ties at vstar, then mean
  float sGt = 0.f;
  int   cGt = 0;
#pragma unroll
  for (int i = 0; i < 16; ++i) {
    unsigned a;
    a = uv[i].x; if (a > vstar) { sGt += __uint_as_float(a); ++cGt; }
    a = uv[i].y; if (a > vstar) { sGt += __uint_as_float(a); ++cGt; }
    a = uv[i].z; if (a > vstar) { sGt += __uint_as_float(a); ++cGt; }
    a = uv[i].w; if (a > vstar) { sGt += __uint_as_float(a); ++cGt; }
  }
  sGt = waveReduceF(sGt);
  cGt = waveReduceI(cGt);
  if (lane == 0) { fws[w] = sGt; waveSum[w] = cGt; }
  __syncthreads();
  if (tid == 0) {
    float s = 0.f;
    int   c = 0;
    for (int i = 0; i < 16; ++i) { s += fws[i]; c += waveSum[i]; }
    float total = s + (float)(KSEL - c) * __uint_as_float(vstar);
    out[row] = total / (float)KSEL;
  }
}

// ---------------------------------------------------------------------------
extern "C" void kernel_launch(void* const* d_in, const int* in_sizes, int n_in,
                              void* d_out, int out_size, void* d_ws, size_t ws_size,
                              hipStream_t stream) {
  const float* x    = (const float*)d_in[0];
  const float* W    = (const float*)d_in[1];
  const float* bias = (const float*)d_in[2];
  float* out    = (float*)d_out;
  float* scores = (float*)d_ws;  // B*N floats = 8 MB

  int blocks1 = (BATCH * NV4) / BDIM;  // 2048
  conv_score_kernel<<<blocks1, BDIM, 0, stream>>>(x, W, bias, scores);
  topk_mean_kernel<<<BATCH, 1024, 0, stream>>>(scores, out);
}

// Round 3
// 197.935 us; speedup vs baseline: 1.1353x; 1.1353x over previous
//
#include <hip/hip_runtime.h>
#include <hip/hip_bf16.h>

#define BDIM   256
#define BATCH  32
#define CH     128
#define NLEN   65536
#define NV4    (NLEN / 4)      // 16384 float4 per row
#define KSEL   6553            // int(65536 * 0.1)
#define VPT    4               // float4 per thread (kernel 1)

typedef float v4f __attribute__((ext_vector_type(4)));  // native vector for
                                                        // __builtin_nontemporal_load

// ---------------------------------------------------------------------------
// Kernel 1: scores[b,n] = |sum_c x[b,c,n]*W[c] + bias|   (memory-bound, 1 GiB)
// Each block owns 1024 consecutive float4 (16 KB of n); thread t accumulates
// 4 float4 at {base + i*256 + t}. Inner loop over c issues 4 contiguous 1KB
// wave-loads per c (16 KB/wave window), unrolled x4 -> 16 loads in flight.
// x is streamed nontemporally (read exactly once); scores stay cached.
// ---------------------------------------------------------------------------
__global__ __launch_bounds__(BDIM) void conv_score_kernel(
    const float* __restrict__ x, const float* __restrict__ W,
    const float* __restrict__ bias, float* __restrict__ scores) {
  __shared__ float sW[CH];
  if (threadIdx.x < CH) sW[threadIdx.x] = W[threadIdx.x];
  __syncthreads();

  const size_t blockStart = (size_t)blockIdx.x * (BDIM * VPT); // float4 units
  const int    row        = (int)(blockStart >> 14);           // / NV4
  const size_t nbase      = blockStart & (NV4 - 1);

  const v4f* xp = (const v4f*)x + (size_t)row * CH * NV4 + nbase
                  + threadIdx.x;

  v4f acc[VPT];
#pragma unroll
  for (int i = 0; i < VPT; ++i) acc[i] = (v4f)0.f;

#pragma unroll 4
  for (int c = 0; c < CH; ++c) {
    const v4f* p = xp + (size_t)c * NV4;
    float w = sW[c];
#pragma unroll
    for (int i = 0; i < VPT; ++i) {
      v4f v = __builtin_nontemporal_load(p + i * BDIM);
      acc[i].x = fmaf(v.x, w, acc[i].x);
      acc[i].y = fmaf(v.y, w, acc[i].y);
      acc[i].z = fmaf(v.z, w, acc[i].z);
      acc[i].w = fmaf(v.w, w, acc[i].w);
    }
  }

  float bb = bias[0];
  v4f* op = (v4f*)scores + blockStart + threadIdx.x;
#pragma unroll
  for (int i = 0; i < VPT; ++i) {
    v4f r;
    r.x = fabsf(acc[i].x + bb);
    r.y = fabsf(acc[i].y + bb);
    r.z = fabsf(acc[i].z + bb);
    r.w = fabsf(acc[i].w + bb);
    op[i * BDIM] = r;
  }
}

// ---------------------------------------------------------------------------
// Kernel 2: exact top-k mean per row via 3-level radix select on float bits.
// Nonnegative floats compare identically as uint32, so radix-select on the
// bit pattern is exact (including ties: all equal bits == equal values).
// ---------------------------------------------------------------------------
__device__ __forceinline__ int waveReduceI(int v) {
#pragma unroll
  for (int o = 32; o > 0; o >>= 1) v += __shfl_down(v, o);
  return v;
}
__device__ __forceinline__ float waveReduceF(float v) {
#pragma unroll
  for (int o = 32; o > 0; o >>= 1) v += __shfl_down(v, o);
  return v;
}

// Descending-suffix search over hist[4096] for the bucket where the running
// (from the top) count crosses `need`. Hierarchical: thread partials (4
// buckets each) -> wave sums -> serial walk of <=16+64+4 steps by thread 0.
// Result: ctrl[0] = bucket T, ctrl[1] = remaining need inside bucket T.
__device__ void findBucket(int* hist, int* part, int* waveSum, int* ctrl,
                           int need_in, int tid, int lane, int w) {
  int base = tid * 4;
  int s = 0;
#pragma unroll
  for (int j = 0; j < 4; ++j) s += hist[4095 - (base + j)];
  part[tid] = s;
  int wsum = waveReduceI(s);
  if (lane == 0) waveSum[w] = wsum;
  __syncthreads();
  if (tid == 0) {
    int cum = 0, need = need_in;
    int cw = 0;
    for (; cw < 15; ++cw) {
      if (cum + waveSum[cw] >= need) break;
      cum += waveSum[cw];
    }
    int ct = cw * 64;
    for (; ct < cw * 64 + 63; ++ct) {
      if (cum + part[ct] >= need) break;
      cum += part[ct];
    }
    int T = 0;
    int p = ct * 4;
#pragma unroll
    for (int j = 0; j < 4; ++j) {
      int b = 4095 - (p + j);
      int c = hist[b];
      if (cum + c >= need) { T = b; break; }
      cum += c;
    }
    ctrl[0] = T;
    ctrl[1] = need - cum;
  }
  __syncthreads();
}

__global__ __launch_bounds__(1024) void topk_mean_kernel(
    const float* __restrict__ scores, float* __restrict__ out) {
  __shared__ int   hist[4096];
  __shared__ int   part[1024];
  __shared__ int   waveSum[16];
  __shared__ float fws[16];
  __shared__ int   ctrl[2];

  const int tid  = threadIdx.x;
  const int lane = tid & 63;
  const int w    = tid >> 6;
  const int row  = blockIdx.x;
  const float4* sp = (const float4*)(scores + (size_t)row * NLEN);

  // Cache the whole row in registers: 16 x uint4 = 64 VGPRs.
  uint4 uv[16];
#pragma unroll
  for (int i = 0; i < 16; ++i) {
    float4 v = sp[i * 1024 + tid];
    uv[i].x = __float_as_uint(v.x);
    uv[i].y = __float_as_uint(v.y);
    uv[i].z = __float_as_uint(v.z);
    uv[i].w = __float_as_uint(v.w);
  }

  // ---- level 1: bits 30..19 (u >> 19 < 4096 since sign bit is 0)
  for (int i = tid; i < 4096; i += 1024) hist[i] = 0;
  __syncthreads();
#pragma unroll
  for (int i = 0; i < 16; ++i) {
    atomicAdd(&hist[uv[i].x >> 19], 1);
    atomicAdd(&hist[uv[i].y >> 19], 1);
    atomicAdd(&hist[uv[i].z >> 19], 1);
    atomicAdd(&hist[uv[i].w >> 19], 1);
  }
  __syncthreads();
  findBucket(hist, part, waveSum, ctrl, KSEL, tid, lane, w);
  const unsigned T1    = (unsigned)ctrl[0];
  const int      need1 = ctrl[1];

  // ---- level 2: bits 18..7 among elements whose top bits == T1
  for (int i = tid; i < 4096; i += 1024) hist[i] = 0;
  __syncthreads();
#pragma unroll
  for (int i = 0; i < 16; ++i) {
    unsigned a;
    a = uv[i].x; if ((a >> 19) == T1) atomicAdd(&hist[(a >> 7) & 4095], 1);
    a = uv[i].y; if ((a >> 19) == T1) atomicAdd(&hist[(a >> 7) & 4095], 1);
    a = uv[i].z; if ((a >> 19) == T1) atomicAdd(&hist[(a >> 7) & 4095], 1);
    a = uv[i].w; if ((a >> 19) == T1) atomicAdd(&hist[(a >> 7) & 4095], 1);
  }
  __syncthreads();
  findBucket(hist, part, waveSum, ctrl, need1, tid, lane, w);
  const unsigned prefix23 = (T1 << 12) | (unsigned)ctrl[0];  // == u >> 7
  const int      need2    = ctrl[1];

  // ---- level 3: bits 6..0 among elements whose (u >> 7) == prefix23
  for (int i = tid; i < 4096; i += 1024) hist[i] = 0;
  __syncthreads();
#pragma unroll
  for (int i = 0; i < 16; ++i) {
    unsigned a;
    a = uv[i].x; if ((a >> 7) == prefix23) atomicAdd(&hist[a & 127], 1);
    a = uv[i].y; if ((a >> 7) == prefix23) atomicAdd(&hist[a & 127], 1);
    a = uv[i].z; if ((a >> 7) == prefix23) atomicAdd(&hist[a & 127], 1);
    a = uv[i].w; if ((a >> 7) == prefix23) atomicAdd(&hist[a & 127], 1);
  }
  __syncthreads();
  findBucket(hist, part, waveSum, ctrl, need2, tid, lane, w);
  const unsigned vstar = (prefix23 << 7) | (unsigned)ctrl[0];  // k-th largest

  // ---- final: sum of strictly-greater + ties at vstar, then mean
  float sGt = 0.f;
  int   cGt = 0;
#pragma unroll
  for (int i = 0; i < 16; ++i) {
    unsigned a;
    a = uv[i].x; if (a > vstar) { sGt += __uint_as_float(a); ++cGt; }
    a = uv[i].y; if (a > vstar) { sGt += __uint_as_float(a); ++cGt; }
    a = uv[i].z; if (a > vstar) { sGt += __uint_as_float(a); ++cGt; }
    a = uv[i].w; if (a > vstar) { sGt += __uint_as_float(a); ++cGt; }
  }
  sGt = waveReduceF(sGt);
  cGt = waveReduceI(cGt);
  if (lane == 0) { fws[w] = sGt; waveSum[w] = cGt; }
  __syncthreads();
  if (tid == 0) {
    float s = 0.f;
    int   c = 0;
    for (int i = 0; i < 16; ++i) { s += fws[i]; c += waveSum[i]; }
    float total = s + (float)(KSEL - c) * __uint_as_float(vstar);
    out[row] = total / (float)KSEL;
  }
}

// ---------------------------------------------------------------------------
extern "C" void kernel_launch(void* const* d_in, const int* in_sizes, int n_in,
                              void* d_out, int out_size, void* d_ws, size_t ws_size,
                              hipStream_t stream) {
  const float* x    = (const float*)d_in[0];
  const float* W    = (const float*)d_in[1];
  const float* bias = (const float*)d_in[2];
  float* out    = (float*)d_out;
  float* scores = (float*)d_ws;  // B*N floats = 8 MB

  int blocks1 = (BATCH * NV4) / (BDIM * VPT);  // 512
  conv_score_kernel<<<blocks1, BDIM, 0, stream>>>(x, W, bias, scores);
  topk_mean_kernel<<<BATCH, 1024, 0, stream>>>(scores, out);
}

// Round 4
// 193.317 us; speedup vs baseline: 1.1624x; 1.0239x over previous
//
#include <hip/hip_runtime.h>
#include <hip/hip_bf16.h>

#define BDIM   256
#define BATCH  32
#define CH     128
#define NLEN   65536
#define NV4    (NLEN / 4)      // 16384 float4 per row
#define KSEL   6553            // int(65536 * 0.1)
#define VPT    4               // float4 per thread (kernel 1)

typedef float v4f __attribute__((ext_vector_type(4)));  // native vector for
                                                        // __builtin_nontemporal_load

// ---------------------------------------------------------------------------
// Kernel 1: scores[b,n] = |sum_c x[b,c,n]*W[c] + bias|   (memory-bound, 1 GiB)
// Each block owns 1024 consecutive float4 (16 KB of n); thread t accumulates
// 4 float4 at {base + i*256 + t}. Inner loop over c issues 4 contiguous 1KB
// wave-loads per c (16 KB/wave window), unrolled x4 -> 16 loads in flight.
// x is streamed nontemporally (read exactly once); scores stay cached.
// ---------------------------------------------------------------------------
__global__ __launch_bounds__(BDIM) void conv_score_kernel(
    const float* __restrict__ x, const float* __restrict__ W,
    const float* __restrict__ bias, float* __restrict__ scores) {
  __shared__ float sW[CH];
  if (threadIdx.x < CH) sW[threadIdx.x] = W[threadIdx.x];
  __syncthreads();

  const size_t blockStart = (size_t)blockIdx.x * (BDIM * VPT); // float4 units
  const int    row        = (int)(blockStart >> 14);           // / NV4
  const size_t nbase      = blockStart & (NV4 - 1);

  const v4f* xp = (const v4f*)x + (size_t)row * CH * NV4 + nbase
                  + threadIdx.x;

  v4f acc[VPT];
#pragma unroll
  for (int i = 0; i < VPT; ++i) acc[i] = (v4f)0.f;

#pragma unroll 4
  for (int c = 0; c < CH; ++c) {
    const v4f* p = xp + (size_t)c * NV4;
    float w = sW[c];
#pragma unroll
    for (int i = 0; i < VPT; ++i) {
      v4f v = __builtin_nontemporal_load(p + i * BDIM);
      acc[i].x = fmaf(v.x, w, acc[i].x);
      acc[i].y = fmaf(v.y, w, acc[i].y);
      acc[i].z = fmaf(v.z, w, acc[i].z);
      acc[i].w = fmaf(v.w, w, acc[i].w);
    }
  }

  float bb = bias[0];
  v4f* op = (v4f*)scores + blockStart + threadIdx.x;
#pragma unroll
  for (int i = 0; i < VPT; ++i) {
    v4f r;
    r.x = fabsf(acc[i].x + bb);
    r.y = fabsf(acc[i].y + bb);
    r.z = fabsf(acc[i].z + bb);
    r.w = fabsf(acc[i].w + bb);
    op[i * BDIM] = r;
  }
}

// ---------------------------------------------------------------------------
// Kernel 2: exact top-k mean per row via 3-level radix select on float bits.
// Nonnegative floats compare identically as uint32, so radix-select on the
// bit pattern is exact (including ties: all equal bits == equal values).
// ---------------------------------------------------------------------------
__device__ __forceinline__ int waveReduceI(int v) {
#pragma unroll
  for (int o = 32; o > 0; o >>= 1) v += __shfl_down(v, o);
  return v;
}
__device__ __forceinline__ float waveReduceF(float v) {
#pragma unroll
  for (int o = 32; o > 0; o >>= 1) v += __shfl_down(v, o);
  return v;
}

// Parallel bucket-select over hist[4096], descending bucket order.
// Thread t owns 4 descending buckets {4095-4t-j}. Exclusive prefix (count of
// all higher buckets) via wave shfl_up scan + per-wave totals. The unique
// thread whose group contains the crossing writes ctrl[0]=bucket,
// ctrl[1]=remaining need inside that bucket.
__device__ void findBucket(int* hist, int* waveSum, int* ctrl,
                           int need, int tid, int lane, int w) {
  int c0 = hist[4095 - 4 * tid];
  int c1 = hist[4094 - 4 * tid];
  int c2 = hist[4093 - 4 * tid];
  int c3 = hist[4092 - 4 * tid];
  int part = c0 + c1 + c2 + c3;

  // inclusive scan within wave (ascending tid = descending buckets)
  int inc = part;
#pragma unroll
  for (int o = 1; o <= 32; o <<= 1) {
    int t = __shfl_up(inc, o);
    if (lane >= o) inc += t;
  }
  if (lane == 63) waveSum[w] = inc;
  __syncthreads();

  int waveBase = 0;
#pragma unroll
  for (int i = 0; i < 16; ++i) waveBase += (i < w) ? waveSum[i] : 0;

  int excl = waveBase + inc - part;  // count in buckets above this group
  if (excl < need && excl + part >= need) {
    int cum = excl, T, rem;
    if (cum + c0 >= need)      { T = 4095 - 4 * tid; rem = need - cum; }
    else if ((cum += c0) + c1 >= need) { T = 4094 - 4 * tid; rem = need - cum; }
    else if ((cum += c1) + c2 >= need) { T = 4093 - 4 * tid; rem = need - cum; }
    else { cum += c2;            T = 4092 - 4 * tid; rem = need - cum; }
    ctrl[0] = T;
    ctrl[1] = rem;
  }
  __syncthreads();
}

__global__ __launch_bounds__(1024) void topk_mean_kernel(
    const float* __restrict__ scores, float* __restrict__ out) {
  __shared__ int   hist[4096];
  __shared__ int   waveSum[16];
  __shared__ float fws[16];
  __shared__ int   ctrl[2];

  const int tid  = threadIdx.x;
  const int lane = tid & 63;
  const int w    = tid >> 6;
  const int row  = blockIdx.x;
  const float4* sp = (const float4*)(scores + (size_t)row * NLEN);

  // Cache the whole row in registers: 16 x uint4 = 64 VGPRs.
  uint4 uv[16];
#pragma unroll
  for (int i = 0; i < 16; ++i) {
    float4 v = sp[i * 1024 + tid];
    uv[i].x = __float_as_uint(v.x);
    uv[i].y = __float_as_uint(v.y);
    uv[i].z = __float_as_uint(v.z);
    uv[i].w = __float_as_uint(v.w);
  }

  // ---- level 1: bits 30..19 (u >> 19 < 4096 since sign bit is 0)
  ((uint4*)hist)[tid] = make_uint4(0, 0, 0, 0);
  __syncthreads();
#pragma unroll
  for (int i = 0; i < 16; ++i) {
    atomicAdd(&hist[uv[i].x >> 19], 1);
    atomicAdd(&hist[uv[i].y >> 19], 1);
    atomicAdd(&hist[uv[i].z >> 19], 1);
    atomicAdd(&hist[uv[i].w >> 19], 1);
  }
  __syncthreads();
  findBucket(hist, waveSum, ctrl, KSEL, tid, lane, w);
  const unsigned T1    = (unsigned)ctrl[0];
  const int      need1 = ctrl[1];

  // ---- level 2: bits 18..7 among elements whose top bits == T1
  ((uint4*)hist)[tid] = make_uint4(0, 0, 0, 0);
  __syncthreads();
#pragma unroll
  for (int i = 0; i < 16; ++i) {
    unsigned a;
    a = uv[i].x; if ((a >> 19) == T1) atomicAdd(&hist[(a >> 7) & 4095], 1);
    a = uv[i].y; if ((a >> 19) == T1) atomicAdd(&hist[(a >> 7) & 4095], 1);
    a = uv[i].z; if ((a >> 19) == T1) atomicAdd(&hist[(a >> 7) & 4095], 1);
    a = uv[i].w; if ((a >> 19) == T1) atomicAdd(&hist[(a >> 7) & 4095], 1);
  }
  __syncthreads();
  findBucket(hist, waveSum, ctrl, need1, tid, lane, w);
  const unsigned prefix23 = (T1 << 12) | (unsigned)ctrl[0];  // == u >> 7
  const int      need2    = ctrl[1];

  // ---- level 3: bits 6..0 among elements whose (u >> 7) == prefix23
  // (only 128 live bins; zero and select over the 4096 array uniformly)
  ((uint4*)hist)[tid] = make_uint4(0, 0, 0, 0);
  __syncthreads();
#pragma unroll
  for (int i = 0; i < 16; ++i) {
    unsigned a;
    a = uv[i].x; if ((a >> 7) == prefix23) atomicAdd(&hist[a & 127], 1);
    a = uv[i].y; if ((a >> 7) == prefix23) atomicAdd(&hist[a & 127], 1);
    a = uv[i].z; if ((a >> 7) == prefix23) atomicAdd(&hist[a & 127], 1);
    a = uv[i].w; if ((a >> 7) == prefix23) atomicAdd(&hist[a & 127], 1);
  }
  __syncthreads();
  findBucket(hist, waveSum, ctrl, need2, tid, lane, w);
  const unsigned vstar = (prefix23 << 7) | (unsigned)ctrl[0];  // k-th largest

  // ---- final: sum of strictly-greater + ties at vstar, then mean
  float sGt = 0.f;
  int   cGt = 0;
#pragma unroll
  for (int i = 0; i < 16; ++i) {
    unsigned a;
    a = uv[i].x; if (a > vstar) { sGt += __uint_as_float(a); ++cGt; }
    a = uv[i].y; if (a > vstar) { sGt += __uint_as_float(a); ++cGt; }
    a = uv[i].z; if (a > vstar) { sGt += __uint_as_float(a); ++cGt; }
    a = uv[i].w; if (a > vstar) { sGt += __uint_as_float(a); ++cGt; }
  }
  sGt = waveReduceF(sGt);
  cGt = waveReduceI(cGt);
  if (lane == 0) { fws[w] = sGt; waveSum[w] = cGt; }
  __syncthreads();
  if (tid == 0) {
    float s = 0.f;
    int   c = 0;
    for (int i = 0; i < 16; ++i) { s += fws[i]; c += waveSum[i]; }
    float total = s + (float)(KSEL - c) * __uint_as_float(vstar);
    out[row] = total / (float)KSEL;
  }
}

// ---------------------------------------------------------------------------
extern "C" void kernel_launch(void* const* d_in, const int* in_sizes, int n_in,
                              void* d_out, int out_size, void* d_ws, size_t ws_size,
                              hipStream_t stream) {
  const float* x    = (const float*)d_in[0];
  const float* W    = (const float*)d_in[1];
  const float* bias = (const float*)d_in[2];
  float* out    = (float*)d_out;
  float* scores = (float*)d_ws;  // B*N floats = 8 MB

  int blocks1 = (BATCH * NV4) / (BDIM * VPT);  // 512
  conv_score_kernel<<<blocks1, BDIM, 0, stream>>>(x, W, bias, scores);
  topk_mean_kernel<<<BATCH, 1024, 0, stream>>>(scores, out);
}